// Round 1
// baseline (1498.018 us; speedup 1.0000x reference)
//
#include <hip/hip_runtime.h>
#include <hip/hip_bf16.h>

// Problem constants
#define NBS   128
#define NF    182      // 20 text + 150 ocr/obj + 12 decode
#define DMODEL 768
#define NH    12
#define HDIM  64
#define SEQT  20
#define ROCR  150
#define NEGV  (-10000.0f)

typedef __attribute__((ext_vector_type(4))) float  f32x4;
typedef __attribute__((ext_vector_type(8))) short  s16x8;
using bf16 = __hip_bfloat16;

// ---------------------------------------------------------------------------
// Kernel 1: pack spatial adjacency (b,150,150,12) fp32 -> bitmask (b,12,150,3) u64
// bit l of word w for (b,h,r) corresponds to key index k = w*64 + l:
//   set iff k in [20,170) and adj[b][r][k-20][h] > 0.5
// ---------------------------------------------------------------------------
__global__ __launch_bounds__(256) void pack_adj(const float* __restrict__ adj,
                                                unsigned long long* __restrict__ bits)
{
    __shared__ float tile[ROCR * NH];       // 150*12 floats = 7.2 KB
    const int b = blockIdx.y, r = blockIdx.x;
    const int tid = threadIdx.x, lane = tid & 63, w = tid >> 6;
    const float* src = adj + ((size_t)b * ROCR + r) * (ROCR * NH);
    for (int i = tid; i < ROCR * NH; i += 256) tile[i] = src[i];
    __syncthreads();
    for (int c = w; c < NH * 3; c += 4) {
        int hh = c / 3, wd = c - hh * 3;
        int k = wd * 64 + lane;
        int j = k - SEQT;                   // index into adjacency key axis
        bool v = false;
        if (j >= 0 && j < ROCR) v = (tile[j * NH + hh] > 0.5f);
        unsigned long long m = __ballot(v);
        if (lane == 0) bits[(((size_t)b * NH + hh) * ROCR + r) * 3 + wd] = m;
    }
}

// ---------------------------------------------------------------------------
// Kernel 2: fused QKV projection.  C = A(23296x768) * W^T + bias -> bf16
// 128x128 tile, BK=32, 4 waves (2x2), mfma_f32_16x16x32_bf16, 4x4 frags/wave.
// gridDim = (182, 18); gy/6 selects {q,k,v}, gy%6 selects 128-col slab.
// ---------------------------------------------------------------------------
__global__ __launch_bounds__(256) void qkv_gemm(
    const float* __restrict__ hs,
    const float* __restrict__ Wq, const float* __restrict__ bq,
    const float* __restrict__ Wk, const float* __restrict__ bk,
    const float* __restrict__ Wv, const float* __restrict__ bv,
    bf16* __restrict__ qw, bf16* __restrict__ kw, bf16* __restrict__ vw)
{
    __shared__ bf16 As[128][32];
    __shared__ bf16 Bsh[128][32];
    const int tid  = threadIdx.x;
    const int lane = tid & 63;
    const int wid  = tid >> 6;
    const int wr   = wid >> 1, wc = wid & 1;      // 2x2 wave grid, 64x64 each
    const int m0   = blockIdx.x * 128;
    const int gn   = blockIdx.y;
    const int which = gn / 6;
    const int n0    = (gn - which * 6) * 128;     // column offset within 768
    const float* W    = (which == 0) ? Wq : (which == 1) ? Wk : Wv;
    const float* bias = (which == 0) ? bq : (which == 1) ? bk : bv;
    bf16* outp        = (which == 0) ? qw : (which == 1) ? kw : vw;

    const int srow = tid >> 3;          // 0..31
    const int scol = (tid & 7) << 2;    // 0,4,...,28

    f32x4 acc[4][4];
    #pragma unroll
    for (int i = 0; i < 4; ++i)
        #pragma unroll
        for (int j = 0; j < 4; ++j) acc[i][j] = (f32x4){0.f, 0.f, 0.f, 0.f};

    for (int k0 = 0; k0 < DMODEL; k0 += 32) {
        #pragma unroll
        for (int rr = 0; rr < 4; ++rr) {
            int r = srow + rr * 32;
            float4 av  = *reinterpret_cast<const float4*>(&hs[(size_t)(m0 + r) * DMODEL + k0 + scol]);
            float4 bv4 = *reinterpret_cast<const float4*>(&W [(size_t)(n0 + r) * DMODEL + k0 + scol]);
            union { ushort4 u; bf16 b[4]; } pa, pb;
            pa.b[0] = __float2bfloat16(av.x);  pa.b[1] = __float2bfloat16(av.y);
            pa.b[2] = __float2bfloat16(av.z);  pa.b[3] = __float2bfloat16(av.w);
            pb.b[0] = __float2bfloat16(bv4.x); pb.b[1] = __float2bfloat16(bv4.y);
            pb.b[2] = __float2bfloat16(bv4.z); pb.b[3] = __float2bfloat16(bv4.w);
            *reinterpret_cast<ushort4*>(&As [r][scol]) = pa.u;
            *reinterpret_cast<ushort4*>(&Bsh[r][scol]) = pb.u;
        }
        __syncthreads();
        s16x8 af[4], bfv[4];
        #pragma unroll
        for (int mi = 0; mi < 4; ++mi)
            af[mi] = *reinterpret_cast<const s16x8*>(&As[wr * 64 + mi * 16 + (lane & 15)][(lane >> 4) * 8]);
        #pragma unroll
        for (int ni = 0; ni < 4; ++ni)
            bfv[ni] = *reinterpret_cast<const s16x8*>(&Bsh[wc * 64 + ni * 16 + (lane & 15)][(lane >> 4) * 8]);
        #pragma unroll
        for (int mi = 0; mi < 4; ++mi)
            #pragma unroll
            for (int ni = 0; ni < 4; ++ni)
                acc[mi][ni] = __builtin_amdgcn_mfma_f32_16x16x32_bf16(af[mi], bfv[ni], acc[mi][ni], 0, 0, 0);
        __syncthreads();
    }
    // epilogue: C row = m0+wr*64+mi*16+(lane>>4)*4+j, col = n0+wc*64+ni*16+(lane&15)
    #pragma unroll
    for (int ni = 0; ni < 4; ++ni) {
        int col = n0 + wc * 64 + ni * 16 + (lane & 15);
        float bcol = bias[col];
        #pragma unroll
        for (int mi = 0; mi < 4; ++mi) {
            #pragma unroll
            for (int j = 0; j < 4; ++j) {
                int row = m0 + wr * 64 + mi * 16 + (lane >> 4) * 4 + j;
                outp[(size_t)row * DMODEL + col] = __float2bfloat16(acc[mi][ni][j] + bcol);
            }
        }
    }
}

// ---------------------------------------------------------------------------
// Kernel 3: attention. One block per (b,h); 4 waves; one q-row per wave-iter.
// K staged in LDS fp32 [182][65] (stride 65 -> bank (k+d)%32, conflict-free
// for lane-per-key scalar reads). probs in LDS, V read coalesced from global.
// Decode rows (>=170) written as zeros. entity mask from max of combined mask.
// ---------------------------------------------------------------------------
__global__ __launch_bounds__(256) void attn_kernel(
    const bf16* __restrict__ qw, const bf16* __restrict__ kw, const bf16* __restrict__ vw,
    const float* __restrict__ amask,               // (128,182) additive {0,-1e4}
    const unsigned long long* __restrict__ bits,   // (128,12,150,3)
    float* __restrict__ out)                       // (128,182,768)
{
    const int bh = blockIdx.x;
    const int b = bh / NH, h = bh % NH;
    const int tid = threadIdx.x, lane = tid & 63, w = tid >> 6;

    __shared__ float Ksh[NF][65];      // 47.3 KB
    __shared__ float qrow[4][64];      // 1 KB
    __shared__ float probs[4][192];    // 3 KB

    for (int i = tid; i < NF * 64; i += 256) {
        int k = i >> 6, d = i & 63;
        Ksh[k][d] = __bfloat162float(kw[((size_t)(b * NF + k)) * DMODEL + h * 64 + d]);
    }
    // decode rows are exactly zero in the reference (entity mask = 0)
    for (int rr = w; rr < NF - 170; rr += 4)
        out[((size_t)(b * NF) + 170 + rr) * DMODEL + h * 64 + lane] = 0.f;
    __syncthreads();

    // 43 uniform iterations per wave so __syncthreads stays legal
    for (int r = w; r < 172; r += 4) {
        const bool active = (r < 170);
        float qd = 0.f;
        if (active) qd = __bfloat162float(qw[((size_t)(b * NF + r)) * DMODEL + h * 64 + lane]);
        qrow[w][lane] = qd;
        __syncthreads();

        float sv[3];
        float maxs = -3.0e38f, maxc = -3.0e38f;
        const unsigned long long* brow =
            bits + (((size_t)b * NH + h) * ROCR + (r >= SEQT ? r - SEQT : 0)) * 3;
        #pragma unroll
        for (int kb = 0; kb < 3; ++kb) {
            int k = kb * 64 + lane;
            bool valid = (k < NF);
            if (valid && active) {
                float amv = amask[b * NF + k];
                float sp;
                if (r < SEQT) {
                    sp = (k >= SEQT + ROCR) ? 0.f : NEGV;
                } else {
                    if (k < SEQT) sp = NEGV;
                    else if (k < SEQT + ROCR) sp = ((brow[kb] >> lane) & 1ull) ? 0.f : NEGV;
                    else sp = 0.f;
                }
                float c = fminf(amv, sp);
                float dot = 0.f;
                #pragma unroll
                for (int d = 0; d < 64; ++d) dot += qrow[w][d] * Ksh[k][d];
                sv[kb] = dot * 0.125f + c;
                maxs = fmaxf(maxs, sv[kb]);
                maxc = fmaxf(maxc, c);
            } else {
                sv[kb] = -3.0e38f;
            }
        }
        #pragma unroll
        for (int off = 1; off < 64; off <<= 1) {
            maxs = fmaxf(maxs, __shfl_xor(maxs, off));
            maxc = fmaxf(maxc, __shfl_xor(maxc, off));
        }
        float e[3];
        float sum = 0.f;
        #pragma unroll
        for (int kb = 0; kb < 3; ++kb) {
            e[kb] = (sv[kb] > -1.0e38f) ? __expf(sv[kb] - maxs) : 0.f;
            sum += e[kb];
        }
        #pragma unroll
        for (int off = 1; off < 64; off <<= 1) sum += __shfl_xor(sum, off);
        float entity = (maxc > -5000.f) ? 1.f : 0.f;   // any attendable key?
        float scale  = active ? (entity / sum) : 0.f;
        #pragma unroll
        for (int kb = 0; kb < 3; ++kb) probs[w][kb * 64 + lane] = e[kb] * scale;
        __syncthreads();

        if (active) {
            float o = 0.f;
            #pragma unroll 2
            for (int k = 0; k < NF; ++k)
                o += probs[w][k] * __bfloat162float(vw[((size_t)(b * NF + k)) * DMODEL + h * 64 + lane]);
            out[((size_t)(b * NF + r)) * DMODEL + h * 64 + lane] = o;
        }
    }
}

// ---------------------------------------------------------------------------
extern "C" void kernel_launch(void* const* d_in, const int* in_sizes, int n_in,
                              void* d_out, int out_size, void* d_ws, size_t ws_size,
                              hipStream_t stream)
{
    const float* hs    = (const float*)d_in[0];
    const float* amask = (const float*)d_in[1];
    const float* adj   = (const float*)d_in[2];
    const float* Wq    = (const float*)d_in[3];
    const float* bq    = (const float*)d_in[4];
    const float* Wk    = (const float*)d_in[5];
    const float* bk    = (const float*)d_in[6];
    const float* Wv    = (const float*)d_in[7];
    const float* bv    = (const float*)d_in[8];
    float* out = (float*)d_out;

    const size_t QKV = (size_t)NBS * NF * DMODEL;   // 17,891,328 elements
    char* ws = (char*)d_ws;
    bf16* qw = (bf16*)ws;
    bf16* kw = (bf16*)(ws + QKV * 2);
    bf16* vw = (bf16*)(ws + QKV * 4);
    unsigned long long* bits = (unsigned long long*)(ws + QKV * 6);
    // total workspace: 107.3 MB (qkv bf16) + 5.5 MB (bitmasks)

    pack_adj<<<dim3(ROCR, NBS), 256, 0, stream>>>(adj, bits);
    qkv_gemm<<<dim3(182, 18), 256, 0, stream>>>(hs, Wq, bq, Wk, bk, Wv, bv, qw, kw, vw);
    attn_kernel<<<dim3(NBS * NH), 256, 0, stream>>>(qw, kw, vw, amask, bits, out);
}

// Round 2
// 382.649 us; speedup vs baseline: 3.9149x; 3.9149x over previous
//
#include <hip/hip_runtime.h>
#include <hip/hip_bf16.h>

// Problem constants
#define NBS   128
#define NF    182      // 20 text + 150 ocr/obj + 12 decode
#define NP    192      // padded N for MFMA tiling
#define DMODEL 768
#define NH    12
#define HDIM  64
#define SEQT  20
#define ROCR  150
#define NEGV  (-10000.0f)

typedef __attribute__((ext_vector_type(4))) float  f32x4;
typedef __attribute__((ext_vector_type(8))) short  s16x8;
using bf16 = __hip_bfloat16;

// ---------------------------------------------------------------------------
// Kernel 1: pack spatial adjacency (b,150,150,12) fp32 -> bitmask (b,12,150,3) u64
// bit l of word w for (b,h,r): key k = w*64+l attendable iff k in [20,170) and
// adj[b][r][k-20][h] > 0.5
// ---------------------------------------------------------------------------
__global__ __launch_bounds__(256) void pack_adj(const float* __restrict__ adj,
                                                unsigned long long* __restrict__ bits)
{
    __shared__ float tile[ROCR * NH];       // 7.2 KB
    const int b = blockIdx.y, r = blockIdx.x;
    const int tid = threadIdx.x, lane = tid & 63, w = tid >> 6;
    const float* src = adj + ((size_t)b * ROCR + r) * (ROCR * NH);
    for (int i = tid; i < ROCR * NH; i += 256) tile[i] = src[i];
    __syncthreads();
    for (int c = w; c < NH * 3; c += 4) {
        int hh = c / 3, wd = c - hh * 3;
        int k = wd * 64 + lane;
        int j = k - SEQT;
        bool v = false;
        if (j >= 0 && j < ROCR) v = (tile[j * NH + hh] > 0.5f);
        unsigned long long m = __ballot(v);
        if (lane == 0) bits[(((size_t)b * NH + hh) * ROCR + r) * 3 + wd] = m;
    }
}

// ---------------------------------------------------------------------------
// Kernel 2: fused QKV projection.  C = A(23296x768) * W^T + bias -> bf16
// q,k written token-major [row][768]; V written TRANSPOSED per head:
// vt[((b*12+h)*64 + d)*192 + key]  (key padded to 192; pad never written)
// ---------------------------------------------------------------------------
__global__ __launch_bounds__(256) void qkv_gemm(
    const float* __restrict__ hs,
    const float* __restrict__ Wq, const float* __restrict__ bq,
    const float* __restrict__ Wk, const float* __restrict__ bk,
    const float* __restrict__ Wv, const float* __restrict__ bv,
    bf16* __restrict__ qw, bf16* __restrict__ kw, bf16* __restrict__ vt)
{
    __shared__ bf16 As[128][32];
    __shared__ bf16 Bsh[128][32];
    const int tid  = threadIdx.x;
    const int lane = tid & 63;
    const int wid  = tid >> 6;
    const int wr   = wid >> 1, wc = wid & 1;
    const int m0   = blockIdx.x * 128;
    const int gn   = blockIdx.y;
    const int which = gn / 6;
    const int n0    = (gn - which * 6) * 128;
    const float* W    = (which == 0) ? Wq : (which == 1) ? Wk : Wv;
    const float* bias = (which == 0) ? bq : (which == 1) ? bk : bv;

    const int srow = tid >> 3;
    const int scol = (tid & 7) << 2;

    f32x4 acc[4][4];
    #pragma unroll
    for (int i = 0; i < 4; ++i)
        #pragma unroll
        for (int j = 0; j < 4; ++j) acc[i][j] = (f32x4){0.f, 0.f, 0.f, 0.f};

    for (int k0 = 0; k0 < DMODEL; k0 += 32) {
        #pragma unroll
        for (int rr = 0; rr < 4; ++rr) {
            int r = srow + rr * 32;
            float4 av  = *reinterpret_cast<const float4*>(&hs[(size_t)(m0 + r) * DMODEL + k0 + scol]);
            float4 bv4 = *reinterpret_cast<const float4*>(&W [(size_t)(n0 + r) * DMODEL + k0 + scol]);
            union { ushort4 u; bf16 b[4]; } pa, pb;
            pa.b[0] = __float2bfloat16(av.x);  pa.b[1] = __float2bfloat16(av.y);
            pa.b[2] = __float2bfloat16(av.z);  pa.b[3] = __float2bfloat16(av.w);
            pb.b[0] = __float2bfloat16(bv4.x); pb.b[1] = __float2bfloat16(bv4.y);
            pb.b[2] = __float2bfloat16(bv4.z); pb.b[3] = __float2bfloat16(bv4.w);
            *reinterpret_cast<ushort4*>(&As [r][scol]) = pa.u;
            *reinterpret_cast<ushort4*>(&Bsh[r][scol]) = pb.u;
        }
        __syncthreads();
        s16x8 af[4], bfv[4];
        #pragma unroll
        for (int mi = 0; mi < 4; ++mi)
            af[mi] = *reinterpret_cast<const s16x8*>(&As[wr * 64 + mi * 16 + (lane & 15)][(lane >> 4) * 8]);
        #pragma unroll
        for (int ni = 0; ni < 4; ++ni)
            bfv[ni] = *reinterpret_cast<const s16x8*>(&Bsh[wc * 64 + ni * 16 + (lane & 15)][(lane >> 4) * 8]);
        #pragma unroll
        for (int mi = 0; mi < 4; ++mi)
            #pragma unroll
            for (int ni = 0; ni < 4; ++ni)
                acc[mi][ni] = __builtin_amdgcn_mfma_f32_16x16x32_bf16(af[mi], bfv[ni], acc[mi][ni], 0, 0, 0);
        __syncthreads();
    }
    bf16* outp = (which == 0) ? qw : kw;
    #pragma unroll
    for (int ni = 0; ni < 4; ++ni) {
        int col = n0 + wc * 64 + ni * 16 + (lane & 15);
        float bcol = bias[col];
        #pragma unroll
        for (int mi = 0; mi < 4; ++mi) {
            #pragma unroll
            for (int j = 0; j < 4; ++j) {
                int row = m0 + wr * 64 + mi * 16 + (lane >> 4) * 4 + j;
                float val = acc[mi][ni][j] + bcol;
                if (which == 2) {
                    int bb = row / NF, key = row - bb * NF;
                    int hh = col >> 6, d = col & 63;
                    vt[(((size_t)bb * NH + hh) * HDIM + d) * NP + key] = __float2bfloat16(val);
                } else {
                    outp[(size_t)row * DMODEL + col] = __float2bfloat16(val);
                }
            }
        }
    }
}

// ---------------------------------------------------------------------------
// Kernel 3: MFMA attention. One block per (b,h), 4 waves, each wave owns
// 16-row bands (bands 0..10; rows >=170 are zero by construction).
// K in swizzled LDS; mask as per-row bit-words; softmax in-register;
// P staged per-wave in swizzled LDS; V^T read direct from global (L2-resident).
// ---------------------------------------------------------------------------
__global__ __launch_bounds__(256) void attn_mfma(
    const bf16* __restrict__ qw, const bf16* __restrict__ kw, const bf16* __restrict__ vt,
    const float* __restrict__ amask,
    const unsigned long long* __restrict__ bits,
    float* __restrict__ out)
{
    const int bh = blockIdx.x;
    const int b = bh / NH, h = bh - b * NH;
    const int tid = threadIdx.x, lane = tid & 63, wid = tid >> 6;
    const int lm = lane & 15, lg = lane >> 4;

    __shared__ bf16 Ksh[NP * HDIM];                 // 24 KB, XOR-swizzled rows
    __shared__ bf16 Psh[4][16 * NP];                // 24 KB, per-wave, swizzled
    __shared__ unsigned long long Lw[NP][3];        // 4.6 KB combined bit-words
    __shared__ unsigned long long aw[3];

    // amask ballot words (wave 0)
    if (wid == 0) {
        #pragma unroll
        for (int w = 0; w < 3; ++w) {
            int k = w * 64 + lane;
            bool v = (k < NF) && (amask[b * NF + k] == 0.0f);
            unsigned long long m = __ballot(v);
            if (lane == 0) aw[w] = m;
        }
    }
    // stage K (bf16, swizzled); rows >=182 zero
    {
        const bf16* kbase = kw + (size_t)b * NF * DMODEL + h * HDIM;
        for (int c = tid; c < NP * 8; c += 256) {       // 16B chunks
            int row = c >> 3, cc = c & 7;
            int byteoff = row * 128 + ((cc * 16) ^ ((row & 7) << 4));
            s16x8 v;
            if (row < NF) v = *reinterpret_cast<const s16x8*>(kbase + (size_t)row * DMODEL + cc * 8);
            else          v = (s16x8){0,0,0,0,0,0,0,0};
            *reinterpret_cast<s16x8*>((char*)Ksh + byteoff) = v;
        }
    }
    // decode rows (170..181) are exactly zero
    {
        float* obase = out + (size_t)b * NF * DMODEL + h * HDIM;
        for (int i = tid; i < 12 * 64; i += 256)
            obase[(size_t)(170 + (i >> 6)) * DMODEL + (i & 63)] = 0.f;
    }
    __syncthreads();
    // combined per-row attendable words
    if (tid < NP) {
        int r = tid;
        unsigned long long s0 = 0, s1 = 0, s2 = 0;
        const unsigned long long DEC = 0xFFFull << 42;   // keys 170..181
        if (r < SEQT) {
            s2 = DEC;                                    // text rows: decode keys only
        } else if (r < SEQT + ROCR) {
            const unsigned long long* bp = bits + (((size_t)b * NH + h) * ROCR + (r - SEQT)) * 3;
            s0 = bp[0]; s1 = bp[1]; s2 = bp[2] | DEC;    // adjacency + decode keys
        }                                                // decode rows: nothing
        Lw[r][0] = s0 & aw[0];
        Lw[r][1] = s1 & aw[1];
        Lw[r][2] = s2 & aw[2];
    }
    __syncthreads();

    const bf16* qbase = qw + (size_t)b * NF * DMODEL + h * HDIM;
    const bf16* vbase = vt + (size_t)bh * HDIM * NP;
    float*      obase = out + (size_t)b * NF * DMODEL + h * HDIM;
    char* Pw = (char*)Psh + wid * (16 * NP * 2);

    for (int band = wid; band < 11; band += 4) {
        const int q0 = band * 16;
        // Q A-fragments (k = ks*32 + lg*8, m = lm)
        s16x8 qf0 = *reinterpret_cast<const s16x8*>(qbase + (size_t)(q0 + lm) * DMODEL + lg * 8);
        s16x8 qf1 = *reinterpret_cast<const s16x8*>(qbase + (size_t)(q0 + lm) * DMODEL + 32 + lg * 8);

        f32x4 sacc[12];
        #pragma unroll
        for (int t = 0; t < 12; ++t) sacc[t] = (f32x4){0.f, 0.f, 0.f, 0.f};
        #pragma unroll
        for (int t = 0; t < 12; ++t) {
            int key = t * 16 + lm;
            const char* kb = (const char*)Ksh + key * 128;
            int sw = (key & 7) << 4;
            s16x8 kf0 = *reinterpret_cast<const s16x8*>(kb + ((lg * 16) ^ sw));
            s16x8 kf1 = *reinterpret_cast<const s16x8*>(kb + ((64 + lg * 16) ^ sw));
            sacc[t] = __builtin_amdgcn_mfma_f32_16x16x32_bf16(qf0, kf0, sacc[t], 0, 0, 0);
            sacc[t] = __builtin_amdgcn_mfma_f32_16x16x32_bf16(qf1, kf1, sacc[t], 0, 0, 0);
        }

        // mask + softmax, fully in-register; D rows = lg*4+j, cols = t*16+lm
        float scl[4];
        #pragma unroll
        for (int j = 0; j < 4; ++j) {
            int row = q0 + lg * 4 + j;
            unsigned long long w0 = Lw[row][0], w1 = Lw[row][1], w2 = Lw[row][2];
            float mx = -3.0e38f;
            #pragma unroll
            for (int t = 0; t < 12; ++t) {
                unsigned long long w = (t < 4) ? w0 : (t < 8) ? w1 : w2;
                int sh = ((t & 3) << 4) + lm;
                float s = sacc[t][j] * 0.125f;
                s = ((w >> sh) & 1ull) ? s : -3.0e38f;
                sacc[t][j] = s;
                mx = fmaxf(mx, s);
            }
            mx = fmaxf(mx, __shfl_xor(mx, 1));
            mx = fmaxf(mx, __shfl_xor(mx, 2));
            mx = fmaxf(mx, __shfl_xor(mx, 4));
            mx = fmaxf(mx, __shfl_xor(mx, 8));
            float sum = 0.f;
            #pragma unroll
            for (int t = 0; t < 12; ++t) {
                float e = (sacc[t][j] > -1.0e37f) ? __expf(sacc[t][j] - mx) : 0.f;
                sacc[t][j] = e;
                sum += e;
            }
            sum += __shfl_xor(sum, 1);
            sum += __shfl_xor(sum, 2);
            sum += __shfl_xor(sum, 4);
            sum += __shfl_xor(sum, 8);
            scl[j] = (mx > -1.0e37f) ? 1.0f / sum : 0.f;
        }

        // write P (bf16, swizzled per row)
        #pragma unroll
        for (int j = 0; j < 4; ++j) {
            int prow = lg * 4 + j;
            int sw = (prow & 7) << 4;
            char* prb = Pw + prow * (NP * 2);
            #pragma unroll
            for (int t = 0; t < 12; ++t) {
                bf16 pv = __float2bfloat16(sacc[t][j] * scl[j]);
                *reinterpret_cast<unsigned short*>(prb + (((t * 16 + lm) * 2) ^ sw)) =
                    *reinterpret_cast<unsigned short*>(&pv);
            }
        }
        asm volatile("s_waitcnt lgkmcnt(0)" ::: "memory");
        __builtin_amdgcn_sched_barrier(0);

        // PV: O[q][d] = P(16x192) x V(192x64); B-frags from global vt (L2)
        f32x4 oacc[4];
        #pragma unroll
        for (int t = 0; t < 4; ++t) oacc[t] = (f32x4){0.f, 0.f, 0.f, 0.f};
        int psw = (lm & 7) << 4;
        #pragma unroll
        for (int ks = 0; ks < 6; ++ks) {
            s16x8 pf = *reinterpret_cast<const s16x8*>(Pw + lm * (NP * 2) + ((ks * 64 + lg * 16) ^ psw));
            #pragma unroll
            for (int t = 0; t < 4; ++t) {
                int d = t * 16 + lm;
                s16x8 vf = *reinterpret_cast<const s16x8*>(vbase + (size_t)d * NP + ks * 32 + lg * 8);
                oacc[t] = __builtin_amdgcn_mfma_f32_16x16x32_bf16(pf, vf, oacc[t], 0, 0, 0);
            }
        }
        #pragma unroll
        for (int j = 0; j < 4; ++j) {
            int row = q0 + lg * 4 + j;
            if (row < 170) {
                #pragma unroll
                for (int t = 0; t < 4; ++t)
                    obase[(size_t)row * DMODEL + t * 16 + lm] = oacc[t][j];
            }
        }
    }
}

// ---------------------------------------------------------------------------
extern "C" void kernel_launch(void* const* d_in, const int* in_sizes, int n_in,
                              void* d_out, int out_size, void* d_ws, size_t ws_size,
                              hipStream_t stream)
{
    const float* hs    = (const float*)d_in[0];
    const float* amask = (const float*)d_in[1];
    const float* adj   = (const float*)d_in[2];
    const float* Wq    = (const float*)d_in[3];
    const float* bq    = (const float*)d_in[4];
    const float* Wk    = (const float*)d_in[5];
    const float* bk    = (const float*)d_in[6];
    const float* Wv    = (const float*)d_in[7];
    const float* bv    = (const float*)d_in[8];
    float* out = (float*)d_out;

    const size_t QKV = (size_t)NBS * NF * DMODEL;          // 17,891,328
    const size_t VT  = (size_t)NBS * NH * HDIM * NP;       // 18,874,368
    char* ws = (char*)d_ws;
    bf16* qw = (bf16*)ws;
    bf16* kw = (bf16*)(ws + QKV * 2);
    bf16* vt = (bf16*)(ws + QKV * 4);
    unsigned long long* bits = (unsigned long long*)(ws + QKV * 4 + VT * 2);
    // workspace: 2*35.8 + 37.7 + 5.5 = ~115 MB

    pack_adj<<<dim3(ROCR, NBS), 256, 0, stream>>>(adj, bits);
    qkv_gemm<<<dim3(182, 18), 256, 0, stream>>>(hs, Wq, bq, Wk, bk, Wv, bv, qw, kw, vt);
    attn_mfma<<<dim3(NBS * NH), 256, 0, stream>>>(qw, kw, vt, amask, bits, out);
}

// Round 3
// 337.130 us; speedup vs baseline: 4.4434x; 1.1350x over previous
//
#include <hip/hip_runtime.h>
#include <hip/hip_bf16.h>

// Problem constants
#define NBS   128
#define NF    182      // 20 text + 150 ocr/obj + 12 decode
#define NP    192      // padded N for MFMA tiling
#define DMODEL 768
#define NH    12
#define HDIM  64
#define SEQT  20
#define ROCR  150
#define NEGV  (-10000.0f)

typedef __attribute__((ext_vector_type(4))) float  f32x4;
typedef __attribute__((ext_vector_type(8))) short  s16x8;
using bf16 = __hip_bfloat16;

// CK-style global->LDS direct copy (16B per lane). LDS dst: low 32 bits of the
// generic pointer are the LDS offset (aperture lives in the high half).
__device__ __forceinline__ void gload_lds16(const void* g, void* l) {
    auto gp = (const __attribute__((address_space(1))) unsigned int*)((unsigned long long)g);
    auto lp = (__attribute__((address_space(3))) unsigned int*)(unsigned int)((unsigned long long)l);
    __builtin_amdgcn_global_load_lds(gp, lp, 16, 0, 0);
}

// ---------------------------------------------------------------------------
// Kernel 0: fp32 -> bf16 pre-convert. hs (17.9M elems) -> hsb; Wq|Wk|Wv -> Wb.
// ---------------------------------------------------------------------------
__global__ __launch_bounds__(256) void convert_bf16(
    const float* __restrict__ hs,
    const float* __restrict__ Wq, const float* __restrict__ Wk, const float* __restrict__ Wv,
    bf16* __restrict__ hsb, bf16* __restrict__ Wb)
{
    const size_t HT = (size_t)NBS * NF * DMODEL / 8;        // 2,236,416
    const size_t WT = 3ull * DMODEL * DMODEL / 8;           // 221,184
    size_t i = (size_t)blockIdx.x * 256 + threadIdx.x;
    if (i >= HT + WT) return;
    const float* src; bf16* dst;
    if (i < HT) {
        size_t e = i * 8; src = hs + e; dst = hsb + e;
    } else {
        size_t e = (i - HT) * 8;
        size_t m = e / ((size_t)DMODEL * DMODEL);
        size_t r = e - m * (size_t)DMODEL * DMODEL;
        src = (m == 0 ? Wq : m == 1 ? Wk : Wv) + r;
        dst = Wb + e;
    }
    float4 a = *reinterpret_cast<const float4*>(src);
    float4 b = *reinterpret_cast<const float4*>(src + 4);
    union { s16x8 v; bf16 h[8]; } u;
    u.h[0] = __float2bfloat16(a.x); u.h[1] = __float2bfloat16(a.y);
    u.h[2] = __float2bfloat16(a.z); u.h[3] = __float2bfloat16(a.w);
    u.h[4] = __float2bfloat16(b.x); u.h[5] = __float2bfloat16(b.y);
    u.h[6] = __float2bfloat16(b.z); u.h[7] = __float2bfloat16(b.w);
    *reinterpret_cast<s16x8*>(dst) = u.v;
}

// ---------------------------------------------------------------------------
// Kernel 1: pack spatial adjacency (b,150,150,12) fp32 -> bitmask (b,12,150,3)
// ---------------------------------------------------------------------------
__global__ __launch_bounds__(256) void pack_adj(const float* __restrict__ adj,
                                                unsigned long long* __restrict__ bits)
{
    __shared__ float tile[ROCR * NH];       // 7.2 KB
    const int b = blockIdx.y, r = blockIdx.x;
    const int tid = threadIdx.x, lane = tid & 63, w = tid >> 6;
    const float* src = adj + ((size_t)b * ROCR + r) * (ROCR * NH);
    for (int i = tid; i < ROCR * NH; i += 256) tile[i] = src[i];
    __syncthreads();
    for (int c = w; c < NH * 3; c += 4) {
        int hh = c / 3, wd = c - hh * 3;
        int k = wd * 64 + lane;
        int j = k - SEQT;
        bool v = false;
        if (j >= 0 && j < ROCR) v = (tile[j * NH + hh] > 0.5f);
        unsigned long long m = __ballot(v);
        if (lane == 0) bits[(((size_t)b * NH + hh) * ROCR + r) * 3 + wd] = m;
    }
}

// ---------------------------------------------------------------------------
// Kernel 2: fused QKV projection, m97 structure.
// C(23296 x 2304) = hsb(23296x768,bf16) x Wb^T(2304x768,bf16) + bias
// 128x128 tile, BK=32, global_load_lds(16B) staging, 4 waves (2x2), 4x4 frags.
// q,k token-major; V transposed per head: vt[(bh*64+d)*192 + key].
// ---------------------------------------------------------------------------
__global__ __launch_bounds__(256) void qkv_gemm(
    const bf16* __restrict__ hsb, const bf16* __restrict__ Wb,
    const float* __restrict__ bq, const float* __restrict__ bk, const float* __restrict__ bv,
    bf16* __restrict__ qw, bf16* __restrict__ kw, bf16* __restrict__ vt)
{
    __shared__ bf16 As[128 * 32];           // 8 KB, row-major [row][32]
    __shared__ bf16 Bs[128 * 32];           // 8 KB
    const int tid  = threadIdx.x;
    const int lane = tid & 63;
    const int wid  = tid >> 6;
    const int wr = wid >> 1, wc = wid & 1;
    const int lm = lane & 15, lg = lane >> 4;
    const int m0 = blockIdx.x * 128;
    const int gy = blockIdx.y;              // 0..17
    const char* gA = (const char*)(hsb + (size_t)m0 * DMODEL);
    const char* gB = (const char*)(Wb  + (size_t)gy * 128 * DMODEL);

    f32x4 acc[4][4];
    #pragma unroll
    for (int i = 0; i < 4; ++i)
        #pragma unroll
        for (int j = 0; j < 4; ++j) acc[i][j] = (f32x4){0.f, 0.f, 0.f, 0.f};

    for (int k0 = 0; k0 < DMODEL; k0 += 32) {
        #pragma unroll
        for (int it = 0; it < 2; ++it) {
            int o = tid * 16 + it * 4096;           // byte offset within 8KB tile
            int row = o >> 6, inb = o & 63;
            size_t gofs = (size_t)row * (DMODEL * 2) + (size_t)k0 * 2 + inb;
            gload_lds16(gA + gofs, (char*)As + o);
            gload_lds16(gB + gofs, (char*)Bs + o);
        }
        __syncthreads();
        s16x8 af[4], bfv[4];
        #pragma unroll
        for (int mi = 0; mi < 4; ++mi)
            af[mi] = *reinterpret_cast<const s16x8*>((char*)As + (wr * 64 + mi * 16 + lm) * 64 + lg * 16);
        #pragma unroll
        for (int ni = 0; ni < 4; ++ni)
            bfv[ni] = *reinterpret_cast<const s16x8*>((char*)Bs + (wc * 64 + ni * 16 + lm) * 64 + lg * 16);
        #pragma unroll
        for (int mi = 0; mi < 4; ++mi)
            #pragma unroll
            for (int ni = 0; ni < 4; ++ni)
                acc[mi][ni] = __builtin_amdgcn_mfma_f32_16x16x32_bf16(af[mi], bfv[ni], acc[mi][ni], 0, 0, 0);
        __syncthreads();
    }

    const int which = gy / 6;
    const int n0    = (gy - which * 6) * 128;       // col offset within 768
    const float* bias = (which == 0) ? bq : (which == 1) ? bk : bv;
    bf16* outp        = (which == 0) ? qw : kw;
    #pragma unroll
    for (int ni = 0; ni < 4; ++ni) {
        int col = n0 + wc * 64 + ni * 16 + lm;
        float bcol = bias[col];
        #pragma unroll
        for (int mi = 0; mi < 4; ++mi) {
            #pragma unroll
            for (int j = 0; j < 4; ++j) {
                int row = m0 + wr * 64 + mi * 16 + lg * 4 + j;
                float val = acc[mi][ni][j] + bcol;
                if (which == 2) {
                    int bb = row / NF, key = row - bb * NF;
                    int hh = col >> 6, d = col & 63;
                    vt[(((size_t)bb * NH + hh) * HDIM + d) * NP + key] = __float2bfloat16(val);
                } else {
                    outp[(size_t)row * DMODEL + col] = __float2bfloat16(val);
                }
            }
        }
    }
}

// ---------------------------------------------------------------------------
// Kernel 3: MFMA attention (unchanged from R2 — verified). One block per
// (b,h), 4 waves; K in swizzled LDS; mask as bit-words; in-register softmax;
// P in per-wave swizzled LDS; V^T direct from global (L2-resident).
// ---------------------------------------------------------------------------
__global__ __launch_bounds__(256) void attn_mfma(
    const bf16* __restrict__ qw, const bf16* __restrict__ kw, const bf16* __restrict__ vt,
    const float* __restrict__ amask,
    const unsigned long long* __restrict__ bits,
    float* __restrict__ out)
{
    const int bh = blockIdx.x;
    const int b = bh / NH, h = bh - b * NH;
    const int tid = threadIdx.x, lane = tid & 63, wid = tid >> 6;
    const int lm = lane & 15, lg = lane >> 4;

    __shared__ bf16 Ksh[NP * HDIM];                 // 24 KB, XOR-swizzled rows
    __shared__ bf16 Psh[4][16 * NP];                // 24 KB, per-wave, swizzled
    __shared__ unsigned long long Lw[NP][3];        // 4.6 KB
    __shared__ unsigned long long aw[3];

    if (wid == 0) {
        #pragma unroll
        for (int w = 0; w < 3; ++w) {
            int k = w * 64 + lane;
            bool v = (k < NF) && (amask[b * NF + k] == 0.0f);
            unsigned long long m = __ballot(v);
            if (lane == 0) aw[w] = m;
        }
    }
    {
        const bf16* kbase = kw + (size_t)b * NF * DMODEL + h * HDIM;
        for (int c = tid; c < NP * 8; c += 256) {
            int row = c >> 3, cc = c & 7;
            int byteoff = row * 128 + ((cc * 16) ^ ((row & 7) << 4));
            s16x8 v;
            if (row < NF) v = *reinterpret_cast<const s16x8*>(kbase + (size_t)row * DMODEL + cc * 8);
            else          v = (s16x8){0,0,0,0,0,0,0,0};
            *reinterpret_cast<s16x8*>((char*)Ksh + byteoff) = v;
        }
    }
    {
        float* obase = out + (size_t)b * NF * DMODEL + h * HDIM;
        for (int i = tid; i < 12 * 64; i += 256)
            obase[(size_t)(170 + (i >> 6)) * DMODEL + (i & 63)] = 0.f;
    }
    __syncthreads();
    if (tid < NP) {
        int r = tid;
        unsigned long long s0 = 0, s1 = 0, s2 = 0;
        const unsigned long long DEC = 0xFFFull << 42;
        if (r < SEQT) {
            s2 = DEC;
        } else if (r < SEQT + ROCR) {
            const unsigned long long* bp = bits + (((size_t)b * NH + h) * ROCR + (r - SEQT)) * 3;
            s0 = bp[0]; s1 = bp[1]; s2 = bp[2] | DEC;
        }
        Lw[r][0] = s0 & aw[0];
        Lw[r][1] = s1 & aw[1];
        Lw[r][2] = s2 & aw[2];
    }
    __syncthreads();

    const bf16* qbase = qw + (size_t)b * NF * DMODEL + h * HDIM;
    const bf16* vbase = vt + (size_t)bh * HDIM * NP;
    float*      obase = out + (size_t)b * NF * DMODEL + h * HDIM;
    char* Pw = (char*)Psh + wid * (16 * NP * 2);

    for (int band = wid; band < 11; band += 4) {
        const int q0 = band * 16;
        s16x8 qf0 = *reinterpret_cast<const s16x8*>(qbase + (size_t)(q0 + lm) * DMODEL + lg * 8);
        s16x8 qf1 = *reinterpret_cast<const s16x8*>(qbase + (size_t)(q0 + lm) * DMODEL + 32 + lg * 8);

        f32x4 sacc[12];
        #pragma unroll
        for (int t = 0; t < 12; ++t) sacc[t] = (f32x4){0.f, 0.f, 0.f, 0.f};
        #pragma unroll
        for (int t = 0; t < 12; ++t) {
            int key = t * 16 + lm;
            const char* kb = (const char*)Ksh + key * 128;
            int sw = (key & 7) << 4;
            s16x8 kf0 = *reinterpret_cast<const s16x8*>(kb + ((lg * 16) ^ sw));
            s16x8 kf1 = *reinterpret_cast<const s16x8*>(kb + ((64 + lg * 16) ^ sw));
            sacc[t] = __builtin_amdgcn_mfma_f32_16x16x32_bf16(qf0, kf0, sacc[t], 0, 0, 0);
            sacc[t] = __builtin_amdgcn_mfma_f32_16x16x32_bf16(qf1, kf1, sacc[t], 0, 0, 0);
        }

        float scl[4];
        #pragma unroll
        for (int j = 0; j < 4; ++j) {
            int row = q0 + lg * 4 + j;
            unsigned long long w0 = Lw[row][0], w1 = Lw[row][1], w2 = Lw[row][2];
            float mx = -3.0e38f;
            #pragma unroll
            for (int t = 0; t < 12; ++t) {
                unsigned long long w = (t < 4) ? w0 : (t < 8) ? w1 : w2;
                int sh = ((t & 3) << 4) + lm;
                float s = sacc[t][j] * 0.125f;
                s = ((w >> sh) & 1ull) ? s : -3.0e38f;
                sacc[t][j] = s;
                mx = fmaxf(mx, s);
            }
            mx = fmaxf(mx, __shfl_xor(mx, 1));
            mx = fmaxf(mx, __shfl_xor(mx, 2));
            mx = fmaxf(mx, __shfl_xor(mx, 4));
            mx = fmaxf(mx, __shfl_xor(mx, 8));
            float sum = 0.f;
            #pragma unroll
            for (int t = 0; t < 12; ++t) {
                float e = (sacc[t][j] > -1.0e37f) ? __expf(sacc[t][j] - mx) : 0.f;
                sacc[t][j] = e;
                sum += e;
            }
            sum += __shfl_xor(sum, 1);
            sum += __shfl_xor(sum, 2);
            sum += __shfl_xor(sum, 4);
            sum += __shfl_xor(sum, 8);
            scl[j] = (mx > -1.0e37f) ? 1.0f / sum : 0.f;
        }

        #pragma unroll
        for (int j = 0; j < 4; ++j) {
            int prow = lg * 4 + j;
            int sw = (prow & 7) << 4;
            char* prb = Pw + prow * (NP * 2);
            #pragma unroll
            for (int t = 0; t < 12; ++t) {
                bf16 pv = __float2bfloat16(sacc[t][j] * scl[j]);
                *reinterpret_cast<unsigned short*>(prb + (((t * 16 + lm) * 2) ^ sw)) =
                    *reinterpret_cast<unsigned short*>(&pv);
            }
        }
        asm volatile("s_waitcnt lgkmcnt(0)" ::: "memory");
        __builtin_amdgcn_sched_barrier(0);

        f32x4 oacc[4];
        #pragma unroll
        for (int t = 0; t < 4; ++t) oacc[t] = (f32x4){0.f, 0.f, 0.f, 0.f};
        int psw = (lm & 7) << 4;
        #pragma unroll
        for (int ks = 0; ks < 6; ++ks) {
            s16x8 pf = *reinterpret_cast<const s16x8*>(Pw + lm * (NP * 2) + ((ks * 64 + lg * 16) ^ psw));
            #pragma unroll
            for (int t = 0; t < 4; ++t) {
                int d = t * 16 + lm;
                s16x8 vf = *reinterpret_cast<const s16x8*>(vbase + (size_t)d * NP + ks * 32 + lg * 8);
                oacc[t] = __builtin_amdgcn_mfma_f32_16x16x32_bf16(pf, vf, oacc[t], 0, 0, 0);
            }
        }
        #pragma unroll
        for (int j = 0; j < 4; ++j) {
            int row = q0 + lg * 4 + j;
            if (row < 170) {
                #pragma unroll
                for (int t = 0; t < 4; ++t)
                    obase[(size_t)row * DMODEL + t * 16 + lm] = oacc[t][j];
            }
        }
    }
}

// ---------------------------------------------------------------------------
extern "C" void kernel_launch(void* const* d_in, const int* in_sizes, int n_in,
                              void* d_out, int out_size, void* d_ws, size_t ws_size,
                              hipStream_t stream)
{
    const float* hs    = (const float*)d_in[0];
    const float* amask = (const float*)d_in[1];
    const float* adj   = (const float*)d_in[2];
    const float* Wq    = (const float*)d_in[3];
    const float* bq    = (const float*)d_in[4];
    const float* Wk    = (const float*)d_in[5];
    const float* bk    = (const float*)d_in[6];
    const float* Wv    = (const float*)d_in[7];
    const float* bv    = (const float*)d_in[8];
    float* out = (float*)d_out;

    const size_t QKV = (size_t)NBS * NF * DMODEL;          // 17,891,328
    const size_t VT  = (size_t)NBS * NH * HDIM * NP;       // 18,874,368
    char* ws = (char*)d_ws;
    bf16* Wb = (bf16*)ws;                                  // 3.5 MB
    bf16* qw = (bf16*)(ws + 3538944ull * 2);
    bf16* kw = (bf16*)(ws + 3538944ull * 2 + QKV * 2);
    bf16* vt = (bf16*)(ws + 3538944ull * 2 + QKV * 4);
    unsigned long long* bits = (unsigned long long*)(ws + 3538944ull * 2 + QKV * 4 + VT * 2);
    // ws total ~118 MB. hsb lives in d_out's tail-free space (attn fully
    // rewrites d_out afterwards, stream-ordered).
    bf16* hsb = (bf16*)d_out;                              // 35.8 MB of 71.6 MB

    const int cvt_blocks = (int)(((size_t)NBS * NF * DMODEL / 8 + 3ull * DMODEL * DMODEL / 8 + 255) / 256);
    convert_bf16<<<cvt_blocks, 256, 0, stream>>>(hs, Wq, Wk, Wv, hsb, Wb);
    pack_adj<<<dim3(ROCR, NBS), 256, 0, stream>>>(adj, bits);
    qkv_gemm<<<dim3(182, 18), 256, 0, stream>>>(hsb, Wb, bq, bk, bv, qw, kw, vt);
    attn_mfma<<<dim3(NBS * NH), 256, 0, stream>>>(qw, kw, vt, amask, bits, out);
}

// Round 4
// 302.674 us; speedup vs baseline: 4.9493x; 1.1138x over previous
//
#include <hip/hip_runtime.h>
#include <hip/hip_bf16.h>

// Problem constants
#define NBS   128
#define NF    182      // 20 text + 150 ocr/obj + 12 decode
#define NP    192      // padded N for MFMA tiling
#define DMODEL 768
#define NH    12
#define HDIM  64
#define SEQT  20
#define ROCR  150
#define NEGV  (-10000.0f)

typedef __attribute__((ext_vector_type(4))) float  f32x4;
typedef __attribute__((ext_vector_type(8))) short  s16x8;
using bf16 = __hip_bfloat16;

// global->LDS direct copy, 16B per lane. LDS dest must be linear (base+lane*16).
__device__ __forceinline__ void gload_lds16(const void* g, void* l) {
    auto gp = (const __attribute__((address_space(1))) unsigned int*)((unsigned long long)g);
    auto lp = (__attribute__((address_space(3))) unsigned int*)(unsigned int)((unsigned long long)l);
    __builtin_amdgcn_global_load_lds(gp, lp, 16, 0, 0);
}

// ---------------------------------------------------------------------------
// Kernel 0: fp32 -> bf16 pre-convert. hs -> hsb; Wq|Wk|Wv -> Wb.
// ---------------------------------------------------------------------------
__global__ __launch_bounds__(256) void convert_bf16(
    const float* __restrict__ hs,
    const float* __restrict__ Wq, const float* __restrict__ Wk, const float* __restrict__ Wv,
    bf16* __restrict__ hsb, bf16* __restrict__ Wb)
{
    const size_t HT = (size_t)NBS * NF * DMODEL / 8;        // 2,236,416
    const size_t WT = 3ull * DMODEL * DMODEL / 8;           // 221,184
    size_t i = (size_t)blockIdx.x * 256 + threadIdx.x;
    if (i >= HT + WT) return;
    const float* src; bf16* dst;
    if (i < HT) {
        size_t e = i * 8; src = hs + e; dst = hsb + e;
    } else {
        size_t e = (i - HT) * 8;
        size_t m = e / ((size_t)DMODEL * DMODEL);
        size_t r = e - m * (size_t)DMODEL * DMODEL;
        src = (m == 0 ? Wq : m == 1 ? Wk : Wv) + r;
        dst = Wb + e;
    }
    float4 a = *reinterpret_cast<const float4*>(src);
    float4 b = *reinterpret_cast<const float4*>(src + 4);
    union { s16x8 v; bf16 h[8]; } u;
    u.h[0] = __float2bfloat16(a.x); u.h[1] = __float2bfloat16(a.y);
    u.h[2] = __float2bfloat16(a.z); u.h[3] = __float2bfloat16(a.w);
    u.h[4] = __float2bfloat16(b.x); u.h[5] = __float2bfloat16(b.y);
    u.h[6] = __float2bfloat16(b.z); u.h[7] = __float2bfloat16(b.w);
    *reinterpret_cast<s16x8*>(dst) = u.v;
}

// ---------------------------------------------------------------------------
// Kernel 1: pack spatial adjacency (b,150,150,12) fp32 -> bitmask (b,12,150,3)
// ---------------------------------------------------------------------------
__global__ __launch_bounds__(256) void pack_adj(const float* __restrict__ adj,
                                                unsigned long long* __restrict__ bits)
{
    __shared__ float tile[ROCR * NH];       // 7.2 KB
    const int b = blockIdx.y, r = blockIdx.x;
    const int tid = threadIdx.x, lane = tid & 63, w = tid >> 6;
    const float* src = adj + ((size_t)b * ROCR + r) * (ROCR * NH);
    for (int i = tid; i < ROCR * NH; i += 256) tile[i] = src[i];
    __syncthreads();
    for (int c = w; c < NH * 3; c += 4) {
        int hh = c / 3, wd = c - hh * 3;
        int k = wd * 64 + lane;
        int j = k - SEQT;
        bool v = false;
        if (j >= 0 && j < ROCR) v = (tile[j * NH + hh] > 0.5f);
        unsigned long long m = __ballot(v);
        if (lane == 0) bits[(((size_t)b * NH + hh) * ROCR + r) * 3 + wd] = m;
    }
}

// ---------------------------------------------------------------------------
// Kernel 2: fused QKV projection. C(23296x2304) = hsb x Wb^T + bias.
// 128x128 tile, BK=64, double-buffered 2-phase pipeline, XOR-swizzled LDS
// (linear gload_lds dest + inverse-swizzled global source + swizzled ds_read:
// physical 16B chunk c of row holds logical chunk c^(row&7) -> ds_read_b128
// fragment loads are 2-way-bank (free)).
// grid = (18 slabs fastest, 182 m-blocks) for A-panel L2/L3 reuse.
// q,k token-major; V transposed per head: vt[(bh*64+d)*192 + key].
// ---------------------------------------------------------------------------
__global__ __launch_bounds__(256) void qkv_gemm(
    const bf16* __restrict__ hsb, const bf16* __restrict__ Wb,
    const float* __restrict__ bq, const float* __restrict__ bk, const float* __restrict__ bv,
    bf16* __restrict__ qw, bf16* __restrict__ kw, bf16* __restrict__ vt)
{
    __shared__ char lds[65536];             // 2 x (A 16KB + B 16KB)
    const int tid  = threadIdx.x;
    const int lane = tid & 63;
    const int wid  = tid >> 6;
    const int wr = wid >> 1, wc = wid & 1;
    const int lm = lane & 15, lg = lane >> 4;
    const int gy = blockIdx.x;              // 0..17 (fastest: same-m0 slabs adjacent)
    const int m0 = blockIdx.y * 128;
    const char* gA = (const char*)hsb + (size_t)m0 * (DMODEL * 2);
    const char* gB = (const char*)Wb  + (size_t)gy * 128 * (DMODEL * 2);

    // staging geometry (per 4KB issue): row = it*32 + tid/8, phys chunk = tid&7
    const int srow = tid >> 3;
    const int pchunk = tid & 7;

    f32x4 acc[4][4];
    #pragma unroll
    for (int i = 0; i < 4; ++i)
        #pragma unroll
        for (int j = 0; j < 4; ++j) acc[i][j] = (f32x4){0.f, 0.f, 0.f, 0.f};

    // prologue: stage K-tile 0 into buffer 0
    #pragma unroll
    for (int it = 0; it < 4; ++it) {
        int row = it * 32 + srow;
        int lc = pchunk ^ (row & 7);                    // logical chunk
        size_t gofs = (size_t)row * (DMODEL * 2) + lc * 16;
        int o = it * 4096 + tid * 16;
        gload_lds16(gA + gofs, lds + o);
        gload_lds16(gB + gofs, lds + 16384 + o);
    }
    asm volatile("s_waitcnt vmcnt(0)" ::: "memory");
    __syncthreads();

    const int arow = wr * 64 + lm;          // + mi*16
    const int brow = wc * 64 + lm;          // + ni*16
    const int rsw = lm & 7;                 // row&7 for all frag rows (mi*16 = 0 mod 8)

    for (int t = 0; t < 12; ++t) {
        const char* Ab = lds + (t & 1) * 32768;
        const char* Bb = Ab + 16384;
        // stage next K-tile into other buffer (overlaps ds_read + MFMA)
        if (t + 1 < 12) {
            char* dst = lds + ((t + 1) & 1) * 32768;
            const char* gAk = gA + (t + 1) * 128;       // 64 bf16 = 128 B
            const char* gBk = gB + (t + 1) * 128;
            #pragma unroll
            for (int it = 0; it < 4; ++it) {
                int row = it * 32 + srow;
                int lc = pchunk ^ (row & 7);
                size_t gofs = (size_t)row * (DMODEL * 2) + lc * 16;
                int o = it * 4096 + tid * 16;
                gload_lds16(gAk + gofs, dst + o);
                gload_lds16(gBk + gofs, dst + 16384 + o);
            }
        }
        // compute current tile: 2 sub-K x 16 MFMA
        #pragma unroll
        for (int kk = 0; kk < 2; ++kk) {
            int c0 = kk * 4 + lg;
            int coff = ((c0 ^ rsw) << 4);
            s16x8 af[4], bfv[4];
            #pragma unroll
            for (int mi = 0; mi < 4; ++mi)
                af[mi] = *reinterpret_cast<const s16x8*>(Ab + (arow + mi * 16) * 128 + coff);
            #pragma unroll
            for (int ni = 0; ni < 4; ++ni)
                bfv[ni] = *reinterpret_cast<const s16x8*>(Bb + (brow + ni * 16) * 128 + coff);
            #pragma unroll
            for (int mi = 0; mi < 4; ++mi)
                #pragma unroll
                for (int ni = 0; ni < 4; ++ni)
                    acc[mi][ni] = __builtin_amdgcn_mfma_f32_16x16x32_bf16(af[mi], bfv[ni], acc[mi][ni], 0, 0, 0);
        }
        asm volatile("s_waitcnt vmcnt(0)" ::: "memory");
        __syncthreads();
    }

    const int which = gy / 6;
    const int n0    = (gy - which * 6) * 128;       // col offset within 768
    const float* bias = (which == 0) ? bq : (which == 1) ? bk : bv;
    bf16* outp        = (which == 0) ? qw : kw;
    #pragma unroll
    for (int ni = 0; ni < 4; ++ni) {
        int col = n0 + wc * 64 + ni * 16 + lm;
        float bcol = bias[col];
        #pragma unroll
        for (int mi = 0; mi < 4; ++mi) {
            #pragma unroll
            for (int j = 0; j < 4; ++j) {
                int row = m0 + wr * 64 + mi * 16 + lg * 4 + j;
                float val = acc[mi][ni][j] + bcol;
                if (which == 2) {
                    int bb = row / NF, key = row - bb * NF;
                    int hh = col >> 6, d = col & 63;
                    vt[(((size_t)bb * NH + hh) * HDIM + d) * NP + key] = __float2bfloat16(val);
                } else {
                    outp[(size_t)row * DMODEL + col] = __float2bfloat16(val);
                }
            }
        }
    }
}

// ---------------------------------------------------------------------------
// Kernel 3: MFMA attention (unchanged — verified). One block per (b,h).
// ---------------------------------------------------------------------------
__global__ __launch_bounds__(256) void attn_mfma(
    const bf16* __restrict__ qw, const bf16* __restrict__ kw, const bf16* __restrict__ vt,
    const float* __restrict__ amask,
    const unsigned long long* __restrict__ bits,
    float* __restrict__ out)
{
    const int bh = blockIdx.x;
    const int b = bh / NH, h = bh - b * NH;
    const int tid = threadIdx.x, lane = tid & 63, wid = tid >> 6;
    const int lm = lane & 15, lg = lane >> 4;

    __shared__ bf16 Ksh[NP * HDIM];                 // 24 KB, XOR-swizzled rows
    __shared__ bf16 Psh[4][16 * NP];                // 24 KB, per-wave, swizzled
    __shared__ unsigned long long Lw[NP][3];        // 4.6 KB
    __shared__ unsigned long long aw[3];

    if (wid == 0) {
        #pragma unroll
        for (int w = 0; w < 3; ++w) {
            int k = w * 64 + lane;
            bool v = (k < NF) && (amask[b * NF + k] == 0.0f);
            unsigned long long m = __ballot(v);
            if (lane == 0) aw[w] = m;
        }
    }
    {
        const bf16* kbase = kw + (size_t)b * NF * DMODEL + h * HDIM;
        for (int c = tid; c < NP * 8; c += 256) {
            int row = c >> 3, cc = c & 7;
            int byteoff = row * 128 + ((cc * 16) ^ ((row & 7) << 4));
            s16x8 v;
            if (row < NF) v = *reinterpret_cast<const s16x8*>(kbase + (size_t)row * DMODEL + cc * 8);
            else          v = (s16x8){0,0,0,0,0,0,0,0};
            *reinterpret_cast<s16x8*>((char*)Ksh + byteoff) = v;
        }
    }
    {
        float* obase = out + (size_t)b * NF * DMODEL + h * HDIM;
        for (int i = tid; i < 12 * 64; i += 256)
            obase[(size_t)(170 + (i >> 6)) * DMODEL + (i & 63)] = 0.f;
    }
    __syncthreads();
    if (tid < NP) {
        int r = tid;
        unsigned long long s0 = 0, s1 = 0, s2 = 0;
        const unsigned long long DEC = 0xFFFull << 42;
        if (r < SEQT) {
            s2 = DEC;
        } else if (r < SEQT + ROCR) {
            const unsigned long long* bp = bits + (((size_t)b * NH + h) * ROCR + (r - SEQT)) * 3;
            s0 = bp[0]; s1 = bp[1]; s2 = bp[2] | DEC;
        }
        Lw[r][0] = s0 & aw[0];
        Lw[r][1] = s1 & aw[1];
        Lw[r][2] = s2 & aw[2];
    }
    __syncthreads();

    const bf16* qbase = qw + (size_t)b * NF * DMODEL + h * HDIM;
    const bf16* vbase = vt + (size_t)bh * HDIM * NP;
    float*      obase = out + (size_t)b * NF * DMODEL + h * HDIM;
    char* Pw = (char*)Psh + wid * (16 * NP * 2);

    for (int band = wid; band < 11; band += 4) {
        const int q0 = band * 16;
        s16x8 qf0 = *reinterpret_cast<const s16x8*>(qbase + (size_t)(q0 + lm) * DMODEL + lg * 8);
        s16x8 qf1 = *reinterpret_cast<const s16x8*>(qbase + (size_t)(q0 + lm) * DMODEL + 32 + lg * 8);

        f32x4 sacc[12];
        #pragma unroll
        for (int t = 0; t < 12; ++t) sacc[t] = (f32x4){0.f, 0.f, 0.f, 0.f};
        #pragma unroll
        for (int t = 0; t < 12; ++t) {
            int key = t * 16 + lm;
            const char* kb = (const char*)Ksh + key * 128;
            int sw = (key & 7) << 4;
            s16x8 kf0 = *reinterpret_cast<const s16x8*>(kb + ((lg * 16) ^ sw));
            s16x8 kf1 = *reinterpret_cast<const s16x8*>(kb + ((64 + lg * 16) ^ sw));
            sacc[t] = __builtin_amdgcn_mfma_f32_16x16x32_bf16(qf0, kf0, sacc[t], 0, 0, 0);
            sacc[t] = __builtin_amdgcn_mfma_f32_16x16x32_bf16(qf1, kf1, sacc[t], 0, 0, 0);
        }

        float scl[4];
        #pragma unroll
        for (int j = 0; j < 4; ++j) {
            int row = q0 + lg * 4 + j;
            unsigned long long w0 = Lw[row][0], w1 = Lw[row][1], w2 = Lw[row][2];
            float mx = -3.0e38f;
            #pragma unroll
            for (int t = 0; t < 12; ++t) {
                unsigned long long w = (t < 4) ? w0 : (t < 8) ? w1 : w2;
                int sh = ((t & 3) << 4) + lm;
                float s = sacc[t][j] * 0.125f;
                s = ((w >> sh) & 1ull) ? s : -3.0e38f;
                sacc[t][j] = s;
                mx = fmaxf(mx, s);
            }
            mx = fmaxf(mx, __shfl_xor(mx, 1));
            mx = fmaxf(mx, __shfl_xor(mx, 2));
            mx = fmaxf(mx, __shfl_xor(mx, 4));
            mx = fmaxf(mx, __shfl_xor(mx, 8));
            float sum = 0.f;
            #pragma unroll
            for (int t = 0; t < 12; ++t) {
                float e = (sacc[t][j] > -1.0e37f) ? __expf(sacc[t][j] - mx) : 0.f;
                sacc[t][j] = e;
                sum += e;
            }
            sum += __shfl_xor(sum, 1);
            sum += __shfl_xor(sum, 2);
            sum += __shfl_xor(sum, 4);
            sum += __shfl_xor(sum, 8);
            scl[j] = (mx > -1.0e37f) ? 1.0f / sum : 0.f;
        }

        #pragma unroll
        for (int j = 0; j < 4; ++j) {
            int prow = lg * 4 + j;
            int sw = (prow & 7) << 4;
            char* prb = Pw + prow * (NP * 2);
            #pragma unroll
            for (int t = 0; t < 12; ++t) {
                bf16 pv = __float2bfloat16(sacc[t][j] * scl[j]);
                *reinterpret_cast<unsigned short*>(prb + (((t * 16 + lm) * 2) ^ sw)) =
                    *reinterpret_cast<unsigned short*>(&pv);
            }
        }
        asm volatile("s_waitcnt lgkmcnt(0)" ::: "memory");
        __builtin_amdgcn_sched_barrier(0);

        f32x4 oacc[4];
        #pragma unroll
        for (int t = 0; t < 4; ++t) oacc[t] = (f32x4){0.f, 0.f, 0.f, 0.f};
        int psw = (lm & 7) << 4;
        #pragma unroll
        for (int ks = 0; ks < 6; ++ks) {
            s16x8 pf = *reinterpret_cast<const s16x8*>(Pw + lm * (NP * 2) + ((ks * 64 + lg * 16) ^ psw));
            #pragma unroll
            for (int t = 0; t < 4; ++t) {
                int d = t * 16 + lm;
                s16x8 vf = *reinterpret_cast<const s16x8*>(vbase + (size_t)d * NP + ks * 32 + lg * 8);
                oacc[t] = __builtin_amdgcn_mfma_f32_16x16x32_bf16(pf, vf, oacc[t], 0, 0, 0);
            }
        }
        #pragma unroll
        for (int j = 0; j < 4; ++j) {
            int row = q0 + lg * 4 + j;
            if (row < 170) {
                #pragma unroll
                for (int t = 0; t < 4; ++t)
                    obase[(size_t)row * DMODEL + t * 16 + lm] = oacc[t][j];
            }
        }
    }
}

// ---------------------------------------------------------------------------
extern "C" void kernel_launch(void* const* d_in, const int* in_sizes, int n_in,
                              void* d_out, int out_size, void* d_ws, size_t ws_size,
                              hipStream_t stream)
{
    const float* hs    = (const float*)d_in[0];
    const float* amask = (const float*)d_in[1];
    const float* adj   = (const float*)d_in[2];
    const float* Wq    = (const float*)d_in[3];
    const float* bq    = (const float*)d_in[4];
    const float* Wk    = (const float*)d_in[5];
    const float* bk    = (const float*)d_in[6];
    const float* Wv    = (const float*)d_in[7];
    const float* bv    = (const float*)d_in[8];
    float* out = (float*)d_out;

    const size_t QKV = (size_t)NBS * NF * DMODEL;          // 17,891,328
    const size_t VT  = (size_t)NBS * NH * HDIM * NP;       // 18,874,368
    char* ws = (char*)d_ws;
    bf16* Wb = (bf16*)ws;                                  // 3.5 MB
    bf16* qw = (bf16*)(ws + 3538944ull * 2);
    bf16* kw = (bf16*)(ws + 3538944ull * 2 + QKV * 2);
    bf16* vt = (bf16*)(ws + 3538944ull * 2 + QKV * 4);
    unsigned long long* bits = (unsigned long long*)(ws + 3538944ull * 2 + QKV * 4 + VT * 2);
    bf16* hsb = (bf16*)d_out;   // attn fully rewrites d_out afterwards (stream-ordered)

    const int cvt_blocks = (int)(((size_t)NBS * NF * DMODEL / 8 + 3ull * DMODEL * DMODEL / 8 + 255) / 256);
    convert_bf16<<<cvt_blocks, 256, 0, stream>>>(hs, Wq, Wk, Wv, hsb, Wb);
    pack_adj<<<dim3(ROCR, NBS), 256, 0, stream>>>(adj, bits);
    qkv_gemm<<<dim3(18, 182), 256, 0, stream>>>(hsb, Wb, bq, bk, bv, qw, kw, vt);
    attn_mfma<<<dim3(NBS * NH), 256, 0, stream>>>(qw, kw, vt, amask, bits, out);
}

// Round 5
// 293.187 us; speedup vs baseline: 5.1094x; 1.0324x over previous
//
#include <hip/hip_runtime.h>
#include <hip/hip_bf16.h>

// Problem constants
#define NBS   128
#define NF    182      // 20 text + 150 ocr/obj + 12 decode
#define NP    192      // padded N for MFMA tiling
#define DMODEL 768
#define NH    12
#define HDIM  64
#define SEQT  20
#define ROCR  150
#define NEGV  (-10000.0f)

typedef __attribute__((ext_vector_type(4))) float  f32x4;
typedef __attribute__((ext_vector_type(8))) short  s16x8;
using bf16 = __hip_bfloat16;

// global->LDS direct copy, 16B per lane. LDS dest must be linear (base+lane*16).
__device__ __forceinline__ void gload_lds16(const void* g, void* l) {
    auto gp = (const __attribute__((address_space(1))) unsigned int*)((unsigned long long)g);
    auto lp = (__attribute__((address_space(3))) unsigned int*)(unsigned int)((unsigned long long)l);
    __builtin_amdgcn_global_load_lds(gp, lp, 16, 0, 0);
}

// ---------------------------------------------------------------------------
// Kernel 0: fp32 -> bf16 pre-convert. hs -> hsb; Wq|Wk|Wv -> Wb.
// ---------------------------------------------------------------------------
__global__ __launch_bounds__(256) void convert_bf16(
    const float* __restrict__ hs,
    const float* __restrict__ Wq, const float* __restrict__ Wk, const float* __restrict__ Wv,
    bf16* __restrict__ hsb, bf16* __restrict__ Wb)
{
    const size_t HT = (size_t)NBS * NF * DMODEL / 8;        // 2,236,416
    const size_t WT = 3ull * DMODEL * DMODEL / 8;           // 221,184
    size_t i = (size_t)blockIdx.x * 256 + threadIdx.x;
    if (i >= HT + WT) return;
    const float* src; bf16* dst;
    if (i < HT) {
        size_t e = i * 8; src = hs + e; dst = hsb + e;
    } else {
        size_t e = (i - HT) * 8;
        size_t m = e / ((size_t)DMODEL * DMODEL);
        size_t r = e - m * (size_t)DMODEL * DMODEL;
        src = (m == 0 ? Wq : m == 1 ? Wk : Wv) + r;
        dst = Wb + e;
    }
    float4 a = *reinterpret_cast<const float4*>(src);
    float4 b = *reinterpret_cast<const float4*>(src + 4);
    union { s16x8 v; bf16 h[8]; } u;
    u.h[0] = __float2bfloat16(a.x); u.h[1] = __float2bfloat16(a.y);
    u.h[2] = __float2bfloat16(a.z); u.h[3] = __float2bfloat16(a.w);
    u.h[4] = __float2bfloat16(b.x); u.h[5] = __float2bfloat16(b.y);
    u.h[6] = __float2bfloat16(b.z); u.h[7] = __float2bfloat16(b.w);
    *reinterpret_cast<s16x8*>(dst) = u.v;
}

// ---------------------------------------------------------------------------
// Kernel 1: pack spatial adjacency (b,150,150,12) fp32 -> bitmask (b,12,150,3)
// ---------------------------------------------------------------------------
__global__ __launch_bounds__(256) void pack_adj(const float* __restrict__ adj,
                                                unsigned long long* __restrict__ bits)
{
    __shared__ float tile[ROCR * NH];       // 7.2 KB
    const int b = blockIdx.y, r = blockIdx.x;
    const int tid = threadIdx.x, lane = tid & 63, w = tid >> 6;
    const float* src = adj + ((size_t)b * ROCR + r) * (ROCR * NH);
    for (int i = tid; i < ROCR * NH; i += 256) tile[i] = src[i];
    __syncthreads();
    for (int c = w; c < NH * 3; c += 4) {
        int hh = c / 3, wd = c - hh * 3;
        int k = wd * 64 + lane;
        int j = k - SEQT;
        bool v = false;
        if (j >= 0 && j < ROCR) v = (tile[j * NH + hh] > 0.5f);
        unsigned long long m = __ballot(v);
        if (lane == 0) bits[(((size_t)b * NH + hh) * ROCR + r) * 3 + wd] = m;
    }
}

// ---------------------------------------------------------------------------
// Kernel 2: fused QKV projection. C(23296x2304) = hsb x Wb^T + bias.
// 128x128 tile, BK=64, double-buffered with COUNTED vmcnt(8) + raw barriers
// (loads stay in flight across compute — T4). XOR-swizzled LDS (linear
// gload_lds dest + inverse-swizzled global src + swizzled ds_read).
// 1D grid, m204 bijective XCD swizzle, m-major (same-A-panel blocks land on
// one XCD's L2).
// q,k token-major; V transposed per head: vt[(bh*64+d)*192 + key].
// ---------------------------------------------------------------------------
__global__ __launch_bounds__(256) void qkv_gemm(
    const bf16* __restrict__ hsb, const bf16* __restrict__ Wb,
    const float* __restrict__ bq, const float* __restrict__ bk, const float* __restrict__ bv,
    bf16* __restrict__ qw, bf16* __restrict__ kw, bf16* __restrict__ vt)
{
    __shared__ char lds[65536];             // 2 x (A 16KB + B 16KB)
    const int tid  = threadIdx.x;
    const int lane = tid & 63;
    const int wid  = tid >> 6;
    const int wr = wid >> 1, wc = wid & 1;
    const int lm = lane & 15, lg = lane >> 4;

    // XCD-bijective remap (m204): flat dispatch id -> contiguous wgid chunk
    // per XCD; wgid m-major so one XCD reuses the same A panel.
    const int flat = blockIdx.x;            // 0..3275
    const int q8 = 3276 / 8, r8 = 3276 % 8; // 409, 4
    const int xcd = flat & 7, off = flat >> 3;
    const int wgid = (xcd < r8 ? xcd * (q8 + 1) : r8 * (q8 + 1) + (xcd - r8) * q8) + off;
    const int my = wgid / 18;
    const int gy = wgid - my * 18;          // 0..17 column slab
    const int m0 = my * 128;

    const char* gA = (const char*)hsb + (size_t)m0 * (DMODEL * 2);
    const char* gB = (const char*)Wb  + (size_t)gy * 128 * (DMODEL * 2);

    // staging geometry (per 4KB issue): row = it*32 + tid/8, phys chunk = tid&7
    const int srow = tid >> 3;
    const int pchunk = tid & 7;

    f32x4 acc[4][4];
    #pragma unroll
    for (int i = 0; i < 4; ++i)
        #pragma unroll
        for (int j = 0; j < 4; ++j) acc[i][j] = (f32x4){0.f, 0.f, 0.f, 0.f};

    const int arow = wr * 64 + lm;          // + mi*16
    const int brow = wc * 64 + lm;          // + ni*16
    const int rsw = lm & 7;

    // stage K-tile kt into buffer bufsel (8 gload_lds per lane-group pass)
    auto STAGE = [&](int kt, int bufsel) {
        char* dst = lds + bufsel * 32768;
        const char* gAk = gA + (size_t)kt * 128;       // 64 bf16 = 128 B
        const char* gBk = gB + (size_t)kt * 128;
        #pragma unroll
        for (int it = 0; it < 4; ++it) {
            int row = it * 32 + srow;
            int lc = pchunk ^ (row & 7);
            size_t gofs = (size_t)row * (DMODEL * 2) + lc * 16;
            int o = it * 4096 + tid * 16;
            gload_lds16(gAk + gofs, dst + o);
            gload_lds16(gBk + gofs, dst + 16384 + o);
        }
    };
    auto COMPUTE = [&](int bufsel) {
        const char* Ab = lds + bufsel * 32768;
        const char* Bb = Ab + 16384;
        #pragma unroll
        for (int kk = 0; kk < 2; ++kk) {
            int coff = ((kk * 4 + lg) ^ rsw) << 4;
            s16x8 af[4], bfv[4];
            #pragma unroll
            for (int mi = 0; mi < 4; ++mi)
                af[mi] = *reinterpret_cast<const s16x8*>(Ab + (arow + mi * 16) * 128 + coff);
            #pragma unroll
            for (int ni = 0; ni < 4; ++ni)
                bfv[ni] = *reinterpret_cast<const s16x8*>(Bb + (brow + ni * 16) * 128 + coff);
            #pragma unroll
            for (int mi = 0; mi < 4; ++mi)
                #pragma unroll
                for (int ni = 0; ni < 4; ++ni)
                    acc[mi][ni] = __builtin_amdgcn_mfma_f32_16x16x32_bf16(af[mi], bfv[ni], acc[mi][ni], 0, 0, 0);
        }
    };

    // prologue: two tiles in flight
    STAGE(0, 0);
    STAGE(1, 1);

    for (int t = 0; t < 11; ++t) {
        // wait stage(t) done; stage(t+1)'s 8 loads remain in flight
        asm volatile("s_waitcnt vmcnt(8)" ::: "memory");
        __builtin_amdgcn_sched_barrier(0);
        __builtin_amdgcn_s_barrier();
        COMPUTE(t & 1);
        __builtin_amdgcn_sched_barrier(0);
        __builtin_amdgcn_s_barrier();           // buf[t&1] free for overwrite
        if (t < 10) STAGE(t + 2, t & 1);
    }
    asm volatile("s_waitcnt vmcnt(0)" ::: "memory");
    __builtin_amdgcn_sched_barrier(0);
    __builtin_amdgcn_s_barrier();
    COMPUTE(1);

    const int which = gy / 6;
    const int n0    = (gy - which * 6) * 128;       // col offset within 768
    const float* bias = (which == 0) ? bq : (which == 1) ? bk : bv;
    bf16* outp        = (which == 0) ? qw : kw;
    #pragma unroll
    for (int ni = 0; ni < 4; ++ni) {
        int col = n0 + wc * 64 + ni * 16 + lm;
        float bcol = bias[col];
        #pragma unroll
        for (int mi = 0; mi < 4; ++mi) {
            #pragma unroll
            for (int j = 0; j < 4; ++j) {
                int row = m0 + wr * 64 + mi * 16 + lg * 4 + j;
                float val = acc[mi][ni][j] + bcol;
                if (which == 2) {
                    int bb = row / NF, key = row - bb * NF;
                    int hh = col >> 6, d = col & 63;
                    vt[(((size_t)bb * NH + hh) * HDIM + d) * NP + key] = __float2bfloat16(val);
                } else {
                    outp[(size_t)row * DMODEL + col] = __float2bfloat16(val);
                }
            }
        }
    }
}

// ---------------------------------------------------------------------------
// Kernel 3: MFMA attention (unchanged — verified). One block per (b,h).
// ---------------------------------------------------------------------------
__global__ __launch_bounds__(256) void attn_mfma(
    const bf16* __restrict__ qw, const bf16* __restrict__ kw, const bf16* __restrict__ vt,
    const float* __restrict__ amask,
    const unsigned long long* __restrict__ bits,
    float* __restrict__ out)
{
    const int bh = blockIdx.x;
    const int b = bh / NH, h = bh - b * NH;
    const int tid = threadIdx.x, lane = tid & 63, wid = tid >> 6;
    const int lm = lane & 15, lg = lane >> 4;

    __shared__ bf16 Ksh[NP * HDIM];                 // 24 KB, XOR-swizzled rows
    __shared__ bf16 Psh[4][16 * NP];                // 24 KB, per-wave, swizzled
    __shared__ unsigned long long Lw[NP][3];        // 4.6 KB
    __shared__ unsigned long long aw[3];

    if (wid == 0) {
        #pragma unroll
        for (int w = 0; w < 3; ++w) {
            int k = w * 64 + lane;
            bool v = (k < NF) && (amask[b * NF + k] == 0.0f);
            unsigned long long m = __ballot(v);
            if (lane == 0) aw[w] = m;
        }
    }
    {
        const bf16* kbase = kw + (size_t)b * NF * DMODEL + h * HDIM;
        for (int c = tid; c < NP * 8; c += 256) {
            int row = c >> 3, cc = c & 7;
            int byteoff = row * 128 + ((cc * 16) ^ ((row & 7) << 4));
            s16x8 v;
            if (row < NF) v = *reinterpret_cast<const s16x8*>(kbase + (size_t)row * DMODEL + cc * 8);
            else          v = (s16x8){0,0,0,0,0,0,0,0};
            *reinterpret_cast<s16x8*>((char*)Ksh + byteoff) = v;
        }
    }
    {
        float* obase = out + (size_t)b * NF * DMODEL + h * HDIM;
        for (int i = tid; i < 12 * 64; i += 256)
            obase[(size_t)(170 + (i >> 6)) * DMODEL + (i & 63)] = 0.f;
    }
    __syncthreads();
    if (tid < NP) {
        int r = tid;
        unsigned long long s0 = 0, s1 = 0, s2 = 0;
        const unsigned long long DEC = 0xFFFull << 42;
        if (r < SEQT) {
            s2 = DEC;
        } else if (r < SEQT + ROCR) {
            const unsigned long long* bp = bits + (((size_t)b * NH + h) * ROCR + (r - SEQT)) * 3;
            s0 = bp[0]; s1 = bp[1]; s2 = bp[2] | DEC;
        }
        Lw[r][0] = s0 & aw[0];
        Lw[r][1] = s1 & aw[1];
        Lw[r][2] = s2 & aw[2];
    }
    __syncthreads();

    const bf16* qbase = qw + (size_t)b * NF * DMODEL + h * HDIM;
    const bf16* vbase = vt + (size_t)bh * HDIM * NP;
    float*      obase = out + (size_t)b * NF * DMODEL + h * HDIM;
    char* Pw = (char*)Psh + wid * (16 * NP * 2);

    for (int band = wid; band < 11; band += 4) {
        const int q0 = band * 16;
        s16x8 qf0 = *reinterpret_cast<const s16x8*>(qbase + (size_t)(q0 + lm) * DMODEL + lg * 8);
        s16x8 qf1 = *reinterpret_cast<const s16x8*>(qbase + (size_t)(q0 + lm) * DMODEL + 32 + lg * 8);

        f32x4 sacc[12];
        #pragma unroll
        for (int t = 0; t < 12; ++t) sacc[t] = (f32x4){0.f, 0.f, 0.f, 0.f};
        #pragma unroll
        for (int t = 0; t < 12; ++t) {
            int key = t * 16 + lm;
            const char* kb = (const char*)Ksh + key * 128;
            int sw = (key & 7) << 4;
            s16x8 kf0 = *reinterpret_cast<const s16x8*>(kb + ((lg * 16) ^ sw));
            s16x8 kf1 = *reinterpret_cast<const s16x8*>(kb + ((64 + lg * 16) ^ sw));
            sacc[t] = __builtin_amdgcn_mfma_f32_16x16x32_bf16(qf0, kf0, sacc[t], 0, 0, 0);
            sacc[t] = __builtin_amdgcn_mfma_f32_16x16x32_bf16(qf1, kf1, sacc[t], 0, 0, 0);
        }

        float scl[4];
        #pragma unroll
        for (int j = 0; j < 4; ++j) {
            int row = q0 + lg * 4 + j;
            unsigned long long w0 = Lw[row][0], w1 = Lw[row][1], w2 = Lw[row][2];
            float mx = -3.0e38f;
            #pragma unroll
            for (int t = 0; t < 12; ++t) {
                unsigned long long w = (t < 4) ? w0 : (t < 8) ? w1 : w2;
                int sh = ((t & 3) << 4) + lm;
                float s = sacc[t][j] * 0.125f;
                s = ((w >> sh) & 1ull) ? s : -3.0e38f;
                sacc[t][j] = s;
                mx = fmaxf(mx, s);
            }
            mx = fmaxf(mx, __shfl_xor(mx, 1));
            mx = fmaxf(mx, __shfl_xor(mx, 2));
            mx = fmaxf(mx, __shfl_xor(mx, 4));
            mx = fmaxf(mx, __shfl_xor(mx, 8));
            float sum = 0.f;
            #pragma unroll
            for (int t = 0; t < 12; ++t) {
                float e = (sacc[t][j] > -1.0e37f) ? __expf(sacc[t][j] - mx) : 0.f;
                sacc[t][j] = e;
                sum += e;
            }
            sum += __shfl_xor(sum, 1);
            sum += __shfl_xor(sum, 2);
            sum += __shfl_xor(sum, 4);
            sum += __shfl_xor(sum, 8);
            scl[j] = (mx > -1.0e37f) ? 1.0f / sum : 0.f;
        }

        #pragma unroll
        for (int j = 0; j < 4; ++j) {
            int prow = lg * 4 + j;
            int sw = (prow & 7) << 4;
            char* prb = Pw + prow * (NP * 2);
            #pragma unroll
            for (int t = 0; t < 12; ++t) {
                bf16 pv = __float2bfloat16(sacc[t][j] * scl[j]);
                *reinterpret_cast<unsigned short*>(prb + (((t * 16 + lm) * 2) ^ sw)) =
                    *reinterpret_cast<unsigned short*>(&pv);
            }
        }
        asm volatile("s_waitcnt lgkmcnt(0)" ::: "memory");
        __builtin_amdgcn_sched_barrier(0);

        f32x4 oacc[4];
        #pragma unroll
        for (int t = 0; t < 4; ++t) oacc[t] = (f32x4){0.f, 0.f, 0.f, 0.f};
        int psw = (lm & 7) << 4;
        #pragma unroll
        for (int ks = 0; ks < 6; ++ks) {
            s16x8 pf = *reinterpret_cast<const s16x8*>(Pw + lm * (NP * 2) + ((ks * 64 + lg * 16) ^ psw));
            #pragma unroll
            for (int t = 0; t < 4; ++t) {
                int d = t * 16 + lm;
                s16x8 vf = *reinterpret_cast<const s16x8*>(vbase + (size_t)d * NP + ks * 32 + lg * 8);
                oacc[t] = __builtin_amdgcn_mfma_f32_16x16x32_bf16(pf, vf, oacc[t], 0, 0, 0);
            }
        }
        #pragma unroll
        for (int j = 0; j < 4; ++j) {
            int row = q0 + lg * 4 + j;
            if (row < 170) {
                #pragma unroll
                for (int t = 0; t < 4; ++t)
                    obase[(size_t)row * DMODEL + t * 16 + lm] = oacc[t][j];
            }
        }
    }
}

// ---------------------------------------------------------------------------
extern "C" void kernel_launch(void* const* d_in, const int* in_sizes, int n_in,
                              void* d_out, int out_size, void* d_ws, size_t ws_size,
                              hipStream_t stream)
{
    const float* hs    = (const float*)d_in[0];
    const float* amask = (const float*)d_in[1];
    const float* adj   = (const float*)d_in[2];
    const float* Wq    = (const float*)d_in[3];
    const float* bq    = (const float*)d_in[4];
    const float* Wk    = (const float*)d_in[5];
    const float* bk    = (const float*)d_in[6];
    const float* Wv    = (const float*)d_in[7];
    const float* bv    = (const float*)d_in[8];
    float* out = (float*)d_out;

    const size_t QKV = (size_t)NBS * NF * DMODEL;          // 17,891,328
    const size_t VT  = (size_t)NBS * NH * HDIM * NP;       // 18,874,368
    char* ws = (char*)d_ws;
    bf16* Wb = (bf16*)ws;                                  // 3.5 MB
    bf16* qw = (bf16*)(ws + 3538944ull * 2);
    bf16* kw = (bf16*)(ws + 3538944ull * 2 + QKV * 2);
    bf16* vt = (bf16*)(ws + 3538944ull * 2 + QKV * 4);
    unsigned long long* bits = (unsigned long long*)(ws + 3538944ull * 2 + QKV * 4 + VT * 2);
    bf16* hsb = (bf16*)d_out;   // attn fully rewrites d_out afterwards (stream-ordered)

    const int cvt_blocks = (int)(((size_t)NBS * NF * DMODEL / 8 + 3ull * DMODEL * DMODEL / 8 + 255) / 256);
    convert_bf16<<<cvt_blocks, 256, 0, stream>>>(hs, Wq, Wk, Wv, hsb, Wb);
    pack_adj<<<dim3(ROCR, NBS), 256, 0, stream>>>(adj, bits);
    qkv_gemm<<<dim3(18 * 182), 256, 0, stream>>>(hsb, Wb, bq, bk, bv, qw, kw, vt);
    attn_mfma<<<dim3(NBS * NH), 256, 0, stream>>>(qw, kw, vt, amask, bits, out);
}